// Round 1
// baseline (779.457 us; speedup 1.0000x reference)
//
#include <hip/hip_runtime.h>
#include <math.h>

// NT-Xent (SimCLR) loss. B=4096, D=256, T=0.5.
// reps = normalize(concat(emb_i, emb_j)) -> z[8192][256] (fp32, in ws)
// denom[r] = sum_{j != r} exp(2 * dot(z[r], z[j]))
// pos[k]   = dot(z[k], z[4096+k])
// loss = (1/8192) * ( 4*sum_k pos[k] - sum_r log(denom[r]) )

#define NROWS 8192
#define NHALF 4096
#define DIM   256
#define CS    4      // column splits of the denom GEMM
#define TM    64     // rows per block
#define NC    64     // column tile
#define KC    64     // K chunk

// ---------------------------------------------------------------- normalize
__global__ __launch_bounds__(256) void normalize_kernel(
    const float* __restrict__ emb_i, const float* __restrict__ emb_j,
    float* __restrict__ z) {
  int row = blockIdx.x;
  int tid = threadIdx.x;
  const float* src = (row < NHALF) ? (emb_i + (size_t)row * DIM)
                                   : (emb_j + (size_t)(row - NHALF) * DIM);
  float x = src[tid];
  float ss = x * x;
  #pragma unroll
  for (int off = 32; off; off >>= 1) ss += __shfl_down(ss, off, 64);
  __shared__ float wsum[4];
  if ((tid & 63) == 0) wsum[tid >> 6] = ss;
  __syncthreads();
  float total = wsum[0] + wsum[1] + wsum[2] + wsum[3];
  float norm = fmaxf(sqrtf(total), 1e-12f);
  z[(size_t)row * DIM + tid] = x / norm;
}

// ------------------------------------------------- fused GEMM + exp + rowsum
// grid: (NROWS/TM, CS). Block (rb, cs) owns rows [rb*64, rb*64+64) and
// columns [cs*2048, (cs+1)*2048); writes partial row sums to denomP[cs][row].
__global__ __launch_bounds__(256) void denom_kernel(
    const float* __restrict__ z, float* __restrict__ denomP) {
  const int rb = blockIdx.x;
  const int cs = blockIdx.y;
  const int row0 = rb * TM;
  const int col_begin = cs * (NROWS / CS);
  const int col_end = col_begin + (NROWS / CS);
  const int tid = threadIdx.x;
  const int tr = tid >> 4;   // 0..15 -> rows 4*tr..4*tr+3
  const int tc = tid & 15;   // 0..15 -> cols 4*tc..4*tc+3

  __shared__ float As[TM][KC + 1];
  __shared__ float Bs[NC][KC + 1];

  float rowsum[4] = {0.f, 0.f, 0.f, 0.f};

  for (int cb = col_begin; cb < col_end; cb += NC) {
    float acc[4][4];
    #pragma unroll
    for (int i = 0; i < 4; ++i)
      #pragma unroll
      for (int j = 0; j < 4; ++j) acc[i][j] = 0.f;

    for (int kc = 0; kc < DIM; kc += KC) {
      // stage A (64 rows x 64 k) and B (64 cols x 64 k), float4 global loads
      #pragma unroll
      for (int p = 0; p < 4; ++p) {
        int r = (tid >> 4) + p * 16;
        int c4 = (tid & 15) * 4;
        float4 va = *(const float4*)&z[(size_t)(row0 + r) * DIM + kc + c4];
        As[r][c4 + 0] = va.x; As[r][c4 + 1] = va.y;
        As[r][c4 + 2] = va.z; As[r][c4 + 3] = va.w;
        float4 vb = *(const float4*)&z[(size_t)(cb + r) * DIM + kc + c4];
        Bs[r][c4 + 0] = vb.x; Bs[r][c4 + 1] = vb.y;
        Bs[r][c4 + 2] = vb.z; Bs[r][c4 + 3] = vb.w;
      }
      __syncthreads();
      #pragma unroll 8
      for (int kk = 0; kk < KC; ++kk) {
        float a[4], b[4];
        #pragma unroll
        for (int i = 0; i < 4; ++i) a[i] = As[tr * 4 + i][kk];
        #pragma unroll
        for (int j = 0; j < 4; ++j) b[j] = Bs[tc * 4 + j][kk];
        #pragma unroll
        for (int i = 0; i < 4; ++i)
          #pragma unroll
          for (int j = 0; j < 4; ++j)
            acc[i][j] = fmaf(a[i], b[j], acc[i][j]);
      }
      __syncthreads();
    }

    // exp(sim/T) = exp(2*sim); skip diagonal
    #pragma unroll
    for (int i = 0; i < 4; ++i) {
      int gi = row0 + tr * 4 + i;
      #pragma unroll
      for (int j = 0; j < 4; ++j) {
        int gj = cb + tc * 4 + j;
        float e = __expf(2.0f * acc[i][j]);
        if (gj != gi) rowsum[i] += e;
      }
    }
  }

  // reduce across the 16 tc lanes (contiguous within a wave, same tr)
  #pragma unroll
  for (int i = 0; i < 4; ++i) {
    float v = rowsum[i];
    v += __shfl_down(v, 8, 16);
    v += __shfl_down(v, 4, 16);
    v += __shfl_down(v, 2, 16);
    v += __shfl_down(v, 1, 16);
    if (tc == 0) denomP[(size_t)cs * NROWS + row0 + tr * 4 + i] = v;
  }
}

// ---------------------------------------------------------------- pos pairs
__global__ __launch_bounds__(256) void pos_kernel(
    const float* __restrict__ z, float* __restrict__ pos) {
  int gwave = (int)((blockIdx.x * blockDim.x + threadIdx.x) >> 6);
  int lane = threadIdx.x & 63;
  for (int k = gwave; k < NHALF; k += 256) {
    float4 a = *(const float4*)&z[(size_t)k * DIM + lane * 4];
    float4 b = *(const float4*)&z[(size_t)(NHALF + k) * DIM + lane * 4];
    float d = a.x * b.x + a.y * b.y + a.z * b.z + a.w * b.w;
    #pragma unroll
    for (int off = 32; off; off >>= 1) d += __shfl_down(d, off, 64);
    if (lane == 0) pos[k] = d;
  }
}

// ------------------------------------------------------------- final reduce
__global__ __launch_bounds__(256) void loss_kernel(
    const float* __restrict__ denomP, const float* __restrict__ pos,
    float* __restrict__ out) {
  int tid = threadIdx.x;
  float partial = 0.f;
  for (int r = tid; r < NROWS; r += 256) {
    float d = denomP[r] + denomP[NROWS + r] + denomP[2 * NROWS + r] +
              denomP[3 * NROWS + r];
    partial -= logf(d);
  }
  for (int k = tid; k < NHALF; k += 256) partial += 4.0f * pos[k];
  #pragma unroll
  for (int off = 32; off; off >>= 1) partial += __shfl_down(partial, off, 64);
  __shared__ float ws2[4];
  if ((tid & 63) == 0) ws2[tid >> 6] = partial;
  __syncthreads();
  if (tid == 0)
    out[0] = (ws2[0] + ws2[1] + ws2[2] + ws2[3]) * (1.0f / NROWS);
}

extern "C" void kernel_launch(void* const* d_in, const int* in_sizes, int n_in,
                              void* d_out, int out_size, void* d_ws,
                              size_t ws_size, hipStream_t stream) {
  const float* emb_i = (const float*)d_in[0];
  const float* emb_j = (const float*)d_in[1];
  float* z = (float*)d_ws;                       // 8192*256 floats (8 MB)
  float* denomP = z + (size_t)NROWS * DIM;       // CS*8192 floats
  float* pos = denomP + (size_t)CS * NROWS;      // 4096 floats
  float* out = (float*)d_out;

  normalize_kernel<<<NROWS, 256, 0, stream>>>(emb_i, emb_j, z);
  dim3 gridB(NROWS / TM, CS);
  denom_kernel<<<gridB, 256, 0, stream>>>(z, denomP);
  pos_kernel<<<64, 256, 0, stream>>>(z, pos);
  loss_kernel<<<1, 256, 0, stream>>>(denomP, pos, out);
}

// Round 2
// 141.844 us; speedup vs baseline: 5.4952x; 5.4952x over previous
//
#include <hip/hip_runtime.h>
#include <math.h>

// NT-Xent (SimCLR) loss. B=4096, D=256, T=0.5.
// zb = bf16(normalize(concat(emb_i, emb_j)))  [8192][256]
// sim = zb @ zb^T via MFMA bf16 (fp32 accumulate)
// denom[r] = sum_{j != r} exp(2*sim[r][j])   (partials per column-block)
// loss = (1/8192) * ( 4*sum_k pos[k] - sum_r log(denom[r]) )

#define NROWS 8192
#define NHALF 4096
#define DIM   256
#define BM    128
#define BN    128
#define BK    64
#define NCB   (NROWS / BN)   // 64 column blocks

typedef __attribute__((ext_vector_type(8))) short bf16x8;
typedef __attribute__((ext_vector_type(4))) float f32x4;

static __device__ __forceinline__ unsigned short f2bf(float x) {
  unsigned int u = __float_as_uint(x);
  unsigned int r = (u + 0x7FFFu + ((u >> 16) & 1u)) >> 16;
  return (unsigned short)r;
}
static __device__ __forceinline__ float bf2f(unsigned short b) {
  return __uint_as_float(((unsigned int)b) << 16);
}

// ---------------------------------------------------------------- normalize
// One wave per row (4 rows/block). Norm computed in fp32, output bf16.
__global__ __launch_bounds__(256) void normalize_kernel(
    const float* __restrict__ emb_i, const float* __restrict__ emb_j,
    unsigned short* __restrict__ zb) {
  int w = threadIdx.x >> 6, lane = threadIdx.x & 63;
  int row = blockIdx.x * 4 + w;
  const float* src = (row < NHALF) ? (emb_i + (size_t)row * DIM)
                                   : (emb_j + (size_t)(row - NHALF) * DIM);
  float4 v = ((const float4*)src)[lane];
  float ss = v.x * v.x + v.y * v.y + v.z * v.z + v.w * v.w;
  #pragma unroll
  for (int off = 32; off; off >>= 1) ss += __shfl_down(ss, off, 64);
  float total = __shfl(ss, 0, 64);
  float inv = 1.0f / fmaxf(sqrtf(total), 1e-12f);
  ushort4 o;
  o.x = f2bf(v.x * inv); o.y = f2bf(v.y * inv);
  o.z = f2bf(v.z * inv); o.w = f2bf(v.w * inv);
  ((ushort4*)&zb[(size_t)row * DIM])[lane] = o;
}

// ------------------------------------------------ MFMA GEMM + exp + rowsum
// grid (64, 64): block (bx, by) computes sim tile rows [bx*128,+128) x cols
// [by*128,+128), applies exp(2*sim) skipping the diagonal, and writes
// per-column-block partial row sums to denomP[by][row].
__global__ __launch_bounds__(256) void denom_kernel(
    const unsigned short* __restrict__ zb, float* __restrict__ denomP) {
  __shared__ unsigned short As[BM * BK];  // 16 KB, row-major [128][64]
  __shared__ unsigned short Bs[BN * BK];  // 16 KB

  const int tid = threadIdx.x;
  const int w = tid >> 6;          // wave 0..3
  const int lane = tid & 63;
  const int wr = w >> 1, wc = w & 1;  // 2x2 wave grid, each owns 64x64
  const int quad = lane >> 4;      // 0..3
  const int m16 = lane & 15;       // 0..15
  const int row0 = blockIdx.x * BM;
  const int col0 = blockIdx.y * BN;

  f32x4 acc[4][4];
  #pragma unroll
  for (int i = 0; i < 4; ++i)
    #pragma unroll
    for (int j = 0; j < 4; ++j) {
      f32x4 z4 = {0.f, 0.f, 0.f, 0.f};
      acc[i][j] = z4;
    }

  for (int kc = 0; kc < DIM; kc += BK) {
    // Stage A[128][64] and B[128][64] bf16 via global_load_lds width=16.
    // Each instr: 64 lanes x 16B = 8 rows x 64 k. Wave w stages rows
    // w*32..w*32+31 (4 instrs each for A and B).
    #pragma unroll
    for (int t = 0; t < 4; ++t) {
      int rbase = w * 32 + t * 8;
      int gr = rbase + (lane >> 3);
      int gk = kc + (lane & 7) * 8;
      __builtin_amdgcn_global_load_lds(
          (const __attribute__((address_space(1))) unsigned int*)
              &zb[(size_t)(row0 + gr) * DIM + gk],
          (__attribute__((address_space(3))) unsigned int*)&As[rbase * BK],
          16, 0, 0);
      __builtin_amdgcn_global_load_lds(
          (const __attribute__((address_space(1))) unsigned int*)
              &zb[(size_t)(col0 + gr) * DIM + gk],
          (__attribute__((address_space(3))) unsigned int*)&Bs[rbase * BK],
          16, 0, 0);
    }
    __syncthreads();

    #pragma unroll
    for (int ks = 0; ks < BK; ks += 32) {
      bf16x8 af[4], bfr[4];
      #pragma unroll
      for (int i = 0; i < 4; ++i)
        af[i] = *(const bf16x8*)&As[(wr * 64 + i * 16 + m16) * BK + ks + quad * 8];
      #pragma unroll
      for (int j = 0; j < 4; ++j)
        bfr[j] = *(const bf16x8*)&Bs[(wc * 64 + j * 16 + m16) * BK + ks + quad * 8];
      #pragma unroll
      for (int i = 0; i < 4; ++i)
        #pragma unroll
        for (int j = 0; j < 4; ++j)
          acc[i][j] = __builtin_amdgcn_mfma_f32_16x16x32_bf16(
              af[i], bfr[j], acc[i][j], 0, 0, 0);
    }
    __syncthreads();
  }

  // Epilogue: exp(2*sim), skip diagonal, per-row partial sums.
  // C layout (16x16x32): col = lane&15, row = (lane>>4)*4 + reg.
  float rs[4][4];  // [i][reg]
  #pragma unroll
  for (int i = 0; i < 4; ++i)
    #pragma unroll
    for (int r = 0; r < 4; ++r) rs[i][r] = 0.f;

  #pragma unroll
  for (int i = 0; i < 4; ++i) {
    #pragma unroll
    for (int j = 0; j < 4; ++j) {
      int gcol = col0 + wc * 64 + j * 16 + m16;
      #pragma unroll
      for (int r = 0; r < 4; ++r) {
        int grow = row0 + wr * 64 + i * 16 + quad * 4 + r;
        float e = __expf(2.0f * acc[i][j][r]);
        rs[i][r] += (grow == gcol) ? 0.f : e;
      }
    }
  }

  // Reduce across the 16 column lanes (same quad).
  #pragma unroll
  for (int i = 0; i < 4; ++i)
    #pragma unroll
    for (int r = 0; r < 4; ++r) {
      float v = rs[i][r];
      v += __shfl_xor(v, 1, 16);
      v += __shfl_xor(v, 2, 16);
      v += __shfl_xor(v, 4, 16);
      v += __shfl_xor(v, 8, 16);
      rs[i][r] = v;
    }

  // Cross-wave (wc=0,1) reduce via LDS (reuse As).
  float* red = (float*)As;  // 256 floats used
  if (m16 == 0) {
    #pragma unroll
    for (int i = 0; i < 4; ++i)
      #pragma unroll
      for (int r = 0; r < 4; ++r)
        red[wc * 128 + wr * 64 + i * 16 + quad * 4 + r] = rs[i][r];
  }
  __syncthreads();
  if (tid < 128)
    denomP[(size_t)blockIdx.y * NROWS + row0 + tid] = red[tid] + red[128 + tid];
}

// ---------------------------------------------------------------- pos pairs
__global__ __launch_bounds__(256) void pos_kernel(
    const unsigned short* __restrict__ zb, float* __restrict__ pos) {
  int gwave = (int)((blockIdx.x * blockDim.x + threadIdx.x) >> 6);
  int lane = threadIdx.x & 63;
  for (int k = gwave; k < NHALF; k += 256) {
    ushort4 a = ((const ushort4*)&zb[(size_t)k * DIM])[lane];
    ushort4 b = ((const ushort4*)&zb[(size_t)(NHALF + k) * DIM])[lane];
    float d = bf2f(a.x) * bf2f(b.x) + bf2f(a.y) * bf2f(b.y) +
              bf2f(a.z) * bf2f(b.z) + bf2f(a.w) * bf2f(b.w);
    #pragma unroll
    for (int off = 32; off; off >>= 1) d += __shfl_down(d, off, 64);
    if (lane == 0) pos[k] = d;
  }
}

// ----------------------------------------------------------- denom -> -log
__global__ __launch_bounds__(256) void reduce_kernel(
    const float* __restrict__ denomP, float* __restrict__ nlogd) {
  int r = blockIdx.x * 256 + threadIdx.x;  // 32 blocks
  float s = 0.f;
  #pragma unroll 8
  for (int b = 0; b < NCB; ++b) s += denomP[(size_t)b * NROWS + r];
  nlogd[r] = -logf(s);
}

// ------------------------------------------------------------- final reduce
__global__ __launch_bounds__(256) void loss_kernel(
    const float* __restrict__ nlogd, const float* __restrict__ pos,
    float* __restrict__ out) {
  int tid = threadIdx.x;
  float partial = 0.f;
  for (int r = tid; r < NROWS; r += 256) partial += nlogd[r];
  for (int k = tid; k < NHALF; k += 256) partial += 4.0f * pos[k];
  #pragma unroll
  for (int off = 32; off; off >>= 1) partial += __shfl_down(partial, off, 64);
  __shared__ float ws2[4];
  if ((tid & 63) == 0) ws2[tid >> 6] = partial;
  __syncthreads();
  if (tid == 0)
    out[0] = (ws2[0] + ws2[1] + ws2[2] + ws2[3]) * (1.0f / NROWS);
}

extern "C" void kernel_launch(void* const* d_in, const int* in_sizes, int n_in,
                              void* d_out, int out_size, void* d_ws,
                              size_t ws_size, hipStream_t stream) {
  const float* emb_i = (const float*)d_in[0];
  const float* emb_j = (const float*)d_in[1];
  unsigned short* zb = (unsigned short*)d_ws;            // 8192*256 bf16 (4 MB)
  float* denomP = (float*)(zb + (size_t)NROWS * DIM);    // 64*8192 f32 (2 MB)
  float* pos = denomP + (size_t)NCB * NROWS;             // 4096 f32
  float* nlogd = pos + NHALF;                            // 8192 f32
  float* out = (float*)d_out;

  normalize_kernel<<<NROWS / 4, 256, 0, stream>>>(emb_i, emb_j, zb);
  dim3 gridB(NROWS / BM, NROWS / BN);
  denom_kernel<<<gridB, 256, 0, stream>>>(zb, denomP);
  pos_kernel<<<64, 256, 0, stream>>>(zb, pos);
  reduce_kernel<<<NROWS / 256, 256, 0, stream>>>(denomP, nlogd);
  loss_kernel<<<1, 256, 0, stream>>>(nlogd, pos, out);
}

// Round 3
// 127.289 us; speedup vs baseline: 6.1235x; 1.1143x over previous
//
#include <hip/hip_runtime.h>
#include <math.h>

// NT-Xent (SimCLR) loss. B=4096, D=256, T=0.5.
// zb = bf16(normalize(concat(emb_i, emb_j)))  [8192][256]
// sim = zb @ zb^T via MFMA bf16; exp(2*sim) is SYMMETRIC, so only the upper
// triangle of 128x128 tiles is computed. Tile (bx,by), bx<by, contributes its
// row sums to rows of block bx (slot by) and its column sums to rows of block
// by (slot bx). Diagonal tiles contribute row sums minus the diagonal.
// loss = (1/8192) * ( 4*sum_k pos[k] - sum_r log(denom[r]) )

#define NROWS 8192
#define NHALF 4096
#define DIM   256
#define BM    128
#define BN    128
#define BK    64
#define NCB   (NROWS / BN)          // 64 row/col blocks
#define NTRI  (NCB * (NCB + 1) / 2) // 2080 triangle tiles

typedef __attribute__((ext_vector_type(8))) short bf16x8;
typedef __attribute__((ext_vector_type(4))) float f32x4;

static __device__ __forceinline__ unsigned short f2bf(float x) {
  unsigned int u = __float_as_uint(x);
  unsigned int r = (u + 0x7FFFu + ((u >> 16) & 1u)) >> 16;
  return (unsigned short)r;
}
static __device__ __forceinline__ float bf2f(unsigned short b) {
  return __uint_as_float(((unsigned int)b) << 16);
}

// ------------------------------------------------------------------- zero
__global__ void zero_kernel(float* __restrict__ out) {
  if (threadIdx.x == 0) out[0] = 0.f;
}

// ---------------------------------------------------------------- normalize
__global__ __launch_bounds__(256) void normalize_kernel(
    const float* __restrict__ emb_i, const float* __restrict__ emb_j,
    unsigned short* __restrict__ zb) {
  int w = threadIdx.x >> 6, lane = threadIdx.x & 63;
  int row = blockIdx.x * 4 + w;
  const float* src = (row < NHALF) ? (emb_i + (size_t)row * DIM)
                                   : (emb_j + (size_t)(row - NHALF) * DIM);
  float4 v = ((const float4*)src)[lane];
  float ss = v.x * v.x + v.y * v.y + v.z * v.z + v.w * v.w;
  #pragma unroll
  for (int off = 32; off; off >>= 1) ss += __shfl_down(ss, off, 64);
  float total = __shfl(ss, 0, 64);
  float inv = 1.0f / fmaxf(sqrtf(total), 1e-12f);
  ushort4 o;
  o.x = f2bf(v.x * inv); o.y = f2bf(v.y * inv);
  o.z = f2bf(v.z * inv); o.w = f2bf(v.w * inv);
  ((ushort4*)&zb[(size_t)row * DIM])[lane] = o;
}

// ------------------------------------------------ MFMA GEMM + exp + sums
__global__ __launch_bounds__(256) void denom_kernel(
    const unsigned short* __restrict__ zb, float* __restrict__ denomP) {
  __shared__ unsigned short As[BM * BK];  // 16 KB
  __shared__ unsigned short Bs[BN * BK];  // 16 KB

  // decode triangle tile id -> (bx, by), bx <= by
  int t = blockIdx.x;
  int by = (int)((sqrtf(8.0f * (float)t + 1.0f) - 1.0f) * 0.5f);
  while ((by + 1) * (by + 2) / 2 <= t) ++by;
  while (by * (by + 1) / 2 > t) --by;
  int bx = t - by * (by + 1) / 2;

  const int tid = threadIdx.x;
  const int w = tid >> 6;
  const int lane = tid & 63;
  const int wr = w >> 1, wc = w & 1;  // 2x2 wave grid, 64x64 each
  const int quad = lane >> 4;
  const int m16 = lane & 15;
  const int row0 = bx * BM;
  const int col0 = by * BN;

  f32x4 acc[4][4];
  #pragma unroll
  for (int i = 0; i < 4; ++i)
    #pragma unroll
    for (int j = 0; j < 4; ++j) {
      f32x4 z4 = {0.f, 0.f, 0.f, 0.f};
      acc[i][j] = z4;
    }

  for (int kc = 0; kc < DIM; kc += BK) {
    #pragma unroll
    for (int tt = 0; tt < 4; ++tt) {
      int rbase = w * 32 + tt * 8;
      int gr = rbase + (lane >> 3);
      int gk = kc + (lane & 7) * 8;
      __builtin_amdgcn_global_load_lds(
          (const __attribute__((address_space(1))) unsigned int*)
              &zb[(size_t)(row0 + gr) * DIM + gk],
          (__attribute__((address_space(3))) unsigned int*)&As[rbase * BK],
          16, 0, 0);
      __builtin_amdgcn_global_load_lds(
          (const __attribute__((address_space(1))) unsigned int*)
              &zb[(size_t)(col0 + gr) * DIM + gk],
          (__attribute__((address_space(3))) unsigned int*)&Bs[rbase * BK],
          16, 0, 0);
    }
    __syncthreads();

    #pragma unroll
    for (int ks = 0; ks < BK; ks += 32) {
      bf16x8 af[4], bfr[4];
      #pragma unroll
      for (int i = 0; i < 4; ++i)
        af[i] = *(const bf16x8*)&As[(wr * 64 + i * 16 + m16) * BK + ks + quad * 8];
      #pragma unroll
      for (int j = 0; j < 4; ++j)
        bfr[j] = *(const bf16x8*)&Bs[(wc * 64 + j * 16 + m16) * BK + ks + quad * 8];
      #pragma unroll
      for (int i = 0; i < 4; ++i)
        #pragma unroll
        for (int j = 0; j < 4; ++j)
          acc[i][j] = __builtin_amdgcn_mfma_f32_16x16x32_bf16(
              af[i], bfr[j], acc[i][j], 0, 0, 0);
    }
    __syncthreads();
  }

  // C layout (16x16x32): col_local = wc*64 + j*16 + m16,
  //                      row_local = wr*64 + i*16 + quad*4 + r.
  float* red = (float*)As;  // 512 floats: [0,256) rowsums, [256,512) colsums

  if (bx != by) {
    float rs[4][4];
    float cs[4] = {0.f, 0.f, 0.f, 0.f};
    #pragma unroll
    for (int i = 0; i < 4; ++i)
      #pragma unroll
      for (int r = 0; r < 4; ++r) rs[i][r] = 0.f;

    #pragma unroll
    for (int i = 0; i < 4; ++i)
      #pragma unroll
      for (int j = 0; j < 4; ++j)
        #pragma unroll
        for (int r = 0; r < 4; ++r) {
          float e = __expf(2.0f * acc[i][j][r]);
          rs[i][r] += e;
          cs[j] += e;
        }

    // rowsum: reduce across the 16 column lanes (same quad)
    #pragma unroll
    for (int i = 0; i < 4; ++i)
      #pragma unroll
      for (int r = 0; r < 4; ++r) {
        float v = rs[i][r];
        v += __shfl_xor(v, 1, 16);
        v += __shfl_xor(v, 2, 16);
        v += __shfl_xor(v, 4, 16);
        v += __shfl_xor(v, 8, 16);
        if (m16 == 0) red[wc * 128 + wr * 64 + i * 16 + quad * 4 + r] = v;
      }
    // colsum: reduce across the 4 quads
    #pragma unroll
    for (int j = 0; j < 4; ++j) {
      float v = cs[j];
      v += __shfl_xor(v, 16, 64);
      v += __shfl_xor(v, 32, 64);
      if (quad == 0) red[256 + wr * 128 + wc * 64 + j * 16 + m16] = v;
    }
    __syncthreads();
    if (tid < 128) {
      denomP[(size_t)by * NROWS + row0 + tid] = red[tid] + red[128 + tid];
    } else {
      int c = tid - 128;
      denomP[(size_t)bx * NROWS + col0 + c] = red[256 + c] + red[384 + c];
    }
  } else {
    // diagonal tile: rowsum only, skip diagonal element
    float rs[4][4];
    #pragma unroll
    for (int i = 0; i < 4; ++i)
      #pragma unroll
      for (int r = 0; r < 4; ++r) rs[i][r] = 0.f;
    #pragma unroll
    for (int i = 0; i < 4; ++i)
      #pragma unroll
      for (int j = 0; j < 4; ++j) {
        int lcol = wc * 64 + j * 16 + m16;
        #pragma unroll
        for (int r = 0; r < 4; ++r) {
          int lrow = wr * 64 + i * 16 + quad * 4 + r;
          float e = __expf(2.0f * acc[i][j][r]);
          rs[i][r] += (lrow == lcol) ? 0.f : e;
        }
      }
    #pragma unroll
    for (int i = 0; i < 4; ++i)
      #pragma unroll
      for (int r = 0; r < 4; ++r) {
        float v = rs[i][r];
        v += __shfl_xor(v, 1, 16);
        v += __shfl_xor(v, 2, 16);
        v += __shfl_xor(v, 4, 16);
        v += __shfl_xor(v, 8, 16);
        if (m16 == 0) red[wc * 128 + wr * 64 + i * 16 + quad * 4 + r] = v;
      }
    __syncthreads();
    if (tid < 128)
      denomP[(size_t)bx * NROWS + row0 + tid] = red[tid] + red[128 + tid];
  }
}

// ------------------------------------------- pos pairs (+ atomic into loss)
__global__ __launch_bounds__(256) void pos_kernel(
    const unsigned short* __restrict__ zb, float* __restrict__ out) {
  int w = threadIdx.x >> 6, lane = threadIdx.x & 63;
  int k = blockIdx.x * 4 + w;
  ushort4 a = ((const ushort4*)&zb[(size_t)k * DIM])[lane];
  ushort4 b = ((const ushort4*)&zb[(size_t)(NHALF + k) * DIM])[lane];
  float d = bf2f(a.x) * bf2f(b.x) + bf2f(a.y) * bf2f(b.y) +
            bf2f(a.z) * bf2f(b.z) + bf2f(a.w) * bf2f(b.w);
  #pragma unroll
  for (int off = 32; off; off >>= 1) d += __shfl_down(d, off, 64);
  __shared__ float s4[4];
  if (lane == 0) s4[w] = d;
  __syncthreads();
  if (threadIdx.x == 0)
    atomicAdd(out, (s4[0] + s4[1] + s4[2] + s4[3]) * (1.0f / 2048.0f));
}

// ------------------------------- denom slots -> -log, atomic into loss
__global__ __launch_bounds__(256) void reduce_kernel(
    const float* __restrict__ denomP, float* __restrict__ out) {
  int tid = threadIdx.x;
  int r = blockIdx.x * 256 + tid;  // 32 blocks
  float s = 0.f;
  #pragma unroll 8
  for (int b = 0; b < NCB; ++b) s += denomP[(size_t)b * NROWS + r];
  float v = -logf(s);
  #pragma unroll
  for (int off = 32; off; off >>= 1) v += __shfl_down(v, off, 64);
  __shared__ float s4[4];
  if ((tid & 63) == 0) s4[tid >> 6] = v;
  __syncthreads();
  if (tid == 0)
    atomicAdd(out, (s4[0] + s4[1] + s4[2] + s4[3]) * (1.0f / 8192.0f));
}

extern "C" void kernel_launch(void* const* d_in, const int* in_sizes, int n_in,
                              void* d_out, int out_size, void* d_ws,
                              size_t ws_size, hipStream_t stream) {
  const float* emb_i = (const float*)d_in[0];
  const float* emb_j = (const float*)d_in[1];
  unsigned short* zb = (unsigned short*)d_ws;            // 4 MB
  float* denomP = (float*)(zb + (size_t)NROWS * DIM);    // 64*8192 f32 (2 MB)
  float* out = (float*)d_out;

  zero_kernel<<<1, 64, 0, stream>>>(out);
  normalize_kernel<<<NROWS / 4, 256, 0, stream>>>(emb_i, emb_j, zb);
  denom_kernel<<<NTRI, 256, 0, stream>>>(zb, denomP);
  pos_kernel<<<NHALF / 4, 256, 0, stream>>>(zb, out);
  reduce_kernel<<<NROWS / 256, 256, 0, stream>>>(denomP, out);
}

// Round 4
// 110.980 us; speedup vs baseline: 7.0234x; 1.1469x over previous
//
#include <hip/hip_runtime.h>
#include <math.h>

// NT-Xent (SimCLR) loss. B=4096, D=256, T=0.5.
// zb = bf16(normalize(concat(emb_i, emb_j)))  [8192][256]
// sim = zb@zb^T via MFMA bf16; exp(2*sim) symmetric -> upper-triangle tiles
// only. Tile (bx,by) bx<=by: rowsums -> denomP[by][rows of bx], colsums
// (bx<by) -> denomP[bx][cols of by]. Diagonal (grow==gcol) skipped globally.
// pos_k = sim[k][k+4096] extracted from tiles with by == bx+32.
// loss = (1/8192) * ( 4*sum_k pos[k] - sum_r log(denom[r]) )

#define NROWS 8192
#define NHALF 4096
#define DIM   256
#define BM    128
#define BN    128
#define BK    64
#define NCB   (NROWS / BN)          // 64 row/col blocks
#define NTRI  (NCB * (NCB + 1) / 2) // 2080 triangle tiles

typedef __attribute__((ext_vector_type(8))) short bf16x8;
typedef __attribute__((ext_vector_type(4))) float f32x4;

static __device__ __forceinline__ unsigned short f2bf(float x) {
  unsigned int u = __float_as_uint(x);
  unsigned int r = (u + 0x7FFFu + ((u >> 16) & 1u)) >> 16;
  return (unsigned short)r;
}

// ------------------------------------------- normalize (also zeroes out[0])
__global__ __launch_bounds__(256) void normalize_kernel(
    const float* __restrict__ emb_i, const float* __restrict__ emb_j,
    unsigned short* __restrict__ zb, float* __restrict__ out) {
  if (blockIdx.x == 0 && threadIdx.x == 0) out[0] = 0.f;
  int w = threadIdx.x >> 6, lane = threadIdx.x & 63;
  int row = blockIdx.x * 4 + w;
  const float* src = (row < NHALF) ? (emb_i + (size_t)row * DIM)
                                   : (emb_j + (size_t)(row - NHALF) * DIM);
  float4 v = ((const float4*)src)[lane];
  float ss = v.x * v.x + v.y * v.y + v.z * v.z + v.w * v.w;
  #pragma unroll
  for (int off = 32; off; off >>= 1) ss += __shfl_down(ss, off, 64);
  float total = __shfl(ss, 0, 64);
  float inv = 1.0f / fmaxf(sqrtf(total), 1e-12f);
  ushort4 o;
  o.x = f2bf(v.x * inv); o.y = f2bf(v.y * inv);
  o.z = f2bf(v.z * inv); o.w = f2bf(v.w * inv);
  ((ushort4*)&zb[(size_t)row * DIM])[lane] = o;
}

// ------------------------------------------------ MFMA GEMM + exp + sums
__global__ __launch_bounds__(256) void denom_kernel(
    const unsigned short* __restrict__ zb, float* __restrict__ denomP,
    float* __restrict__ posv) {
  __shared__ unsigned short As[BM * BK];  // 16 KB
  __shared__ unsigned short Bs[BN * BK];  // 16 KB

  // decode triangle tile id -> (bx, by), bx <= by
  int t = blockIdx.x;
  int by = (int)((sqrtf(8.0f * (float)t + 1.0f) - 1.0f) * 0.5f);
  while ((by + 1) * (by + 2) / 2 <= t) ++by;
  while (by * (by + 1) / 2 > t) --by;
  int bx = t - by * (by + 1) / 2;

  const int tid = threadIdx.x;
  const int w = tid >> 6;
  const int lane = tid & 63;
  const int wr = w >> 1, wc = w & 1;  // 2x2 wave grid, 64x64 each
  const int quad = lane >> 4;
  const int m16 = lane & 15;
  const int row0 = bx * BM;
  const int col0 = by * BN;

  f32x4 acc[4][4];
  #pragma unroll
  for (int i = 0; i < 4; ++i)
    #pragma unroll
    for (int j = 0; j < 4; ++j) {
      f32x4 z4 = {0.f, 0.f, 0.f, 0.f};
      acc[i][j] = z4;
    }

  for (int kc = 0; kc < DIM; kc += BK) {
    #pragma unroll
    for (int tt = 0; tt < 4; ++tt) {
      int rbase = w * 32 + tt * 8;
      int gr = rbase + (lane >> 3);
      int gk = kc + (lane & 7) * 8;
      __builtin_amdgcn_global_load_lds(
          (const __attribute__((address_space(1))) unsigned int*)
              &zb[(size_t)(row0 + gr) * DIM + gk],
          (__attribute__((address_space(3))) unsigned int*)&As[rbase * BK],
          16, 0, 0);
      __builtin_amdgcn_global_load_lds(
          (const __attribute__((address_space(1))) unsigned int*)
              &zb[(size_t)(col0 + gr) * DIM + gk],
          (__attribute__((address_space(3))) unsigned int*)&Bs[rbase * BK],
          16, 0, 0);
    }
    __syncthreads();

    #pragma unroll
    for (int ks = 0; ks < BK; ks += 32) {
      bf16x8 af[4], bfr[4];
      #pragma unroll
      for (int i = 0; i < 4; ++i)
        af[i] = *(const bf16x8*)&As[(wr * 64 + i * 16 + m16) * BK + ks + quad * 8];
      #pragma unroll
      for (int j = 0; j < 4; ++j)
        bfr[j] = *(const bf16x8*)&Bs[(wc * 64 + j * 16 + m16) * BK + ks + quad * 8];
      #pragma unroll
      for (int i = 0; i < 4; ++i)
        #pragma unroll
        for (int j = 0; j < 4; ++j)
          acc[i][j] = __builtin_amdgcn_mfma_f32_16x16x32_bf16(
              af[i], bfr[j], acc[i][j], 0, 0, 0);
    }
    __syncthreads();
  }

  // pos extraction: only tiles with col0 == row0 + NHALF hold pair elements.
  if (col0 - row0 == NHALF) {
    #pragma unroll
    for (int i = 0; i < 4; ++i)
      #pragma unroll
      for (int j = 0; j < 4; ++j) {
        int gcol = col0 + wc * 64 + j * 16 + m16;
        #pragma unroll
        for (int r = 0; r < 4; ++r) {
          int grow = row0 + wr * 64 + i * 16 + quad * 4 + r;
          if (gcol - grow == NHALF) posv[grow] = acc[i][j][r];
        }
      }
  }

  // Unified epilogue: e = exp(2*sim); skip the global diagonal (grow==gcol,
  // only occurs in bx==by tiles); accumulate row and column sums.
  // C layout (16x16x32): col = wc*64 + j*16 + m16,
  //                      row = wr*64 + i*16 + quad*4 + r.
  float rs[4][4];
  float cs[4] = {0.f, 0.f, 0.f, 0.f};
  #pragma unroll
  for (int i = 0; i < 4; ++i)
    #pragma unroll
    for (int r = 0; r < 4; ++r) rs[i][r] = 0.f;

  #pragma unroll
  for (int i = 0; i < 4; ++i)
    #pragma unroll
    for (int j = 0; j < 4; ++j) {
      int gcol = col0 + wc * 64 + j * 16 + m16;
      #pragma unroll
      for (int r = 0; r < 4; ++r) {
        int grow = row0 + wr * 64 + i * 16 + quad * 4 + r;
        float e = (grow == gcol) ? 0.f : __expf(2.0f * acc[i][j][r]);
        rs[i][r] += e;
        cs[j] += e;
      }
    }

  float* red = (float*)As;  // 512 floats: [0,256) rowsums, [256,512) colsums

  // rowsum: reduce across the 16 column lanes (same quad)
  #pragma unroll
  for (int i = 0; i < 4; ++i)
    #pragma unroll
    for (int r = 0; r < 4; ++r) {
      float v = rs[i][r];
      v += __shfl_xor(v, 1, 16);
      v += __shfl_xor(v, 2, 16);
      v += __shfl_xor(v, 4, 16);
      v += __shfl_xor(v, 8, 16);
      if (m16 == 0) red[wc * 128 + wr * 64 + i * 16 + quad * 4 + r] = v;
    }
  // colsum: reduce across the 4 quads
  #pragma unroll
  for (int j = 0; j < 4; ++j) {
    float v = cs[j];
    v += __shfl_xor(v, 16, 64);
    v += __shfl_xor(v, 32, 64);
    if (quad == 0) red[256 + wr * 128 + wc * 64 + j * 16 + m16] = v;
  }
  __syncthreads();

  if (tid < 128) {
    denomP[(size_t)by * NROWS + row0 + tid] = red[tid] + red[128 + tid];
  } else if (bx != by) {
    int c = tid - 128;
    denomP[(size_t)bx * NROWS + col0 + c] = red[256 + c] + red[384 + c];
  }
}

// -------------------- denom slots -> -log; + 4*pos; atomic into loss
__global__ __launch_bounds__(256) void reduce_kernel(
    const float* __restrict__ denomP, const float* __restrict__ posv,
    float* __restrict__ out) {
  int tid = threadIdx.x;
  int r = blockIdx.x * 256 + tid;  // 32 blocks cover 8192 rows
  float s = 0.f;
  #pragma unroll 8
  for (int b = 0; b < NCB; ++b) s += denomP[(size_t)b * NROWS + r];
  float v = -logf(s);
  if (r < NHALF) v += 4.0f * posv[r];
  #pragma unroll
  for (int off = 32; off; off >>= 1) v += __shfl_down(v, off, 64);
  __shared__ float s4[4];
  if ((tid & 63) == 0) s4[tid >> 6] = v;
  __syncthreads();
  if (tid == 0)
    atomicAdd(out, (s4[0] + s4[1] + s4[2] + s4[3]) * (1.0f / 8192.0f));
}

extern "C" void kernel_launch(void* const* d_in, const int* in_sizes, int n_in,
                              void* d_out, int out_size, void* d_ws,
                              size_t ws_size, hipStream_t stream) {
  const float* emb_i = (const float*)d_in[0];
  const float* emb_j = (const float*)d_in[1];
  unsigned short* zb = (unsigned short*)d_ws;            // 4 MB
  float* denomP = (float*)(zb + (size_t)NROWS * DIM);    // 64*8192 f32 (2 MB)
  float* posv = denomP + (size_t)NCB * NROWS;            // 4096 f32
  float* out = (float*)d_out;

  normalize_kernel<<<NROWS / 4, 256, 0, stream>>>(emb_i, emb_j, zb, out);
  denom_kernel<<<NTRI, 256, 0, stream>>>(zb, denomP, posv);
  reduce_kernel<<<NROWS / 256, 256, 0, stream>>>(denomP, posv, out);
}